// Round 3
// baseline (661.598 us; speedup 1.0000x reference)
//
#include <hip/hip_runtime.h>

#define BB 256
#define TT 1024
#define II 3
#define HH 128
#define OO 3
#define BT 8              // batch elements per block
#define NBLK (BB / BT)    // 32 blocks
#define NT 512            // 8 waves: 4 MFMA compute + 2 xp + 1 hid-store + 1 proj

typedef __attribute__((ext_vector_type(8))) short short8;   // 8 bf16 (4 VGPR)
typedef __attribute__((ext_vector_type(4))) float f32x4;
typedef __attribute__((ext_vector_type(4))) unsigned int uint4v;
typedef __attribute__((ext_vector_type(2))) unsigned int uint2v;

#if __has_builtin(__builtin_amdgcn_exp2f)
#define EXP2F __builtin_amdgcn_exp2f
#else
#define EXP2F exp2f
#endif
#if __has_builtin(__builtin_amdgcn_rcpf)
#define RCPF __builtin_amdgcn_rcpf
#else
#define RCPF(x) (1.0f / (x))
#endif

__device__ __forceinline__ float fast_tanh(float x) {
    float e = EXP2F(x * 2.885390081777927f);
    return 1.0f - 2.0f * RCPF(e + 1.0f);
}

// LDS-only barrier: does not drain vmcnt, global stores stay in flight.
__device__ __forceinline__ void bar_lds() {
    asm volatile("s_waitcnt lgkmcnt(0)\n\ts_barrier" ::: "memory");
}

template <int CTRL>
__device__ __forceinline__ float dpp_add(float p) {
    return p + __uint_as_float(__builtin_amdgcn_update_dpp(
        0, (int)__float_as_uint(p), CTRL, 0xF, 0xF, true));
}
#define DPP_XOR1 0xB1          // quad_perm [1,0,3,2]
#define DPP_XOR2 0x4E          // quad_perm [2,3,0,1]
#define DPP_HALF_MIRROR 0x141  // lane ^ 7 within 8-lane half-rows

// pack 2 f32 -> 2 bf16 (lo half = first arg), HW RNE
__device__ __forceinline__ unsigned int bf16pk(float a, float b) {
    unsigned int r;
    asm("v_cvt_pk_bf16_f32 %0, %1, %2" : "=v"(r) : "v"(a), "v"(b));
    return r;
}
__device__ __forceinline__ float f_lo16(unsigned int p) { return __uint_as_float(p << 16); }
__device__ __forceinline__ float f_hi16(unsigned int p) { return __uint_as_float(p & 0xffff0000u); }

__device__ __forceinline__ f32x4 MFMA(uint4v a, uint4v b, f32x4 c) {
    return __builtin_amdgcn_mfma_f32_16x16x32_bf16(
        __builtin_bit_cast(short8, a), __builtin_bit_cast(short8, b), c, 0, 0, 0);
}

// LDS swizzle: XOR the 16B-chunk index with the batch index to break the
// 256B/512B row-stride bank pathology (row stride == 0 mod 32 banks).
// ushort arrays (chunks of 8 ushorts):
__device__ __forceinline__ int swzH(int bb, int k) { return (((k >> 3) ^ bb) << 3) | (k & 7); }
// float arrays (chunks of 4 floats):
__device__ __forceinline__ int swzF(int bb, int k) { return (((k >> 2) ^ bb) << 2) | (k & 3); }

// 32 blocks, one per 8 batch elements. One s_barrier per timestep.
// Waves 0-3 (MFMA): wave wv owns output rows [wv*32, wv*32+32) as two 16-row
//   tiles. h_new[128 x 8] = tanh(W_hh @ h[128 x 8] + xp) via
//   mfma_f32_16x16x32_bf16 with split-bf16 (hi+lo) operands:
//   acc = Whi*hhi + Whi*hlo + Wlo*hhi  (+xp as the C-init).
//   Fragment layout assumption: arg0 lane&15 = M-row, arg1 lane&15 = N-col,
//   k = 8*(lane>>4)+e; D: col=lane&15, row=(lane>>4)*4+reg (m89-verified).
// Wave 4,5: xp[t+1] = Wih @ x[t+1] + biases (exact fp32), double-buffered.
// Wave 6: hid stores (from fp32 H32 copy). Wave 7: out projection.
__global__ __launch_bounds__(NT) void rnn_kernel(
    const float* __restrict__ x,     // [B,T,I]
    const float* __restrict__ Wih,   // [H,I]
    const float* __restrict__ Whh,   // [H,H]
    const float* __restrict__ bih,   // [H]
    const float* __restrict__ bhh,   // [H]
    const float* __restrict__ h0,    // [1,H]
    const float* __restrict__ Wout,  // [O,H]
    const float* __restrict__ bout,  // [O]
    float* __restrict__ out,         // [B,T,O]
    float* __restrict__ hid)         // [B,T,H]
{
    __shared__ __align__(16) float4 xs[TT][BT];        // 128 KB staged inputs
    __shared__ __align__(16) ushort Hhi[2][BT][HH];    // 4 KB  hidden hi-bf16
    __shared__ __align__(16) ushort Hlo[2][BT][HH];    // 4 KB  hidden lo-bf16
    __shared__ __align__(16) float  H32[2][BT][HH];    // 8 KB  hidden fp32
    __shared__ __align__(16) float  XP[2][BT][HH];     // 8 KB  input projection

    const int tid = threadIdx.x;
    const int b0 = blockIdx.x * BT;

    // ---- stage x for 8 batches ----
    const float* xb = x + (size_t)b0 * TT * II;
    for (int idx = tid; idx < BT * TT * II; idx += NT) {
        int bb = idx / (TT * II);
        int r = idx - bb * (TT * II);
        int t = r / II;
        int c = r - t * II;
        ((float*)&xs[t][bb])[c] = xb[idx];
    }
    // ---- init hiddens[-1] = h0 ----
    for (int idx = tid; idx < BT * HH; idx += NT) {
        int bb = idx >> 7, h = idx & (HH - 1);
        float v = h0[h];
        unsigned int p = bf16pk(v, 0.f);
        float vh = f_lo16(p);
        unsigned int q = bf16pk(v - vh, 0.f);
        Hhi[0][bb][swzH(bb, h)] = (ushort)(p & 0xffffu);
        Hlo[0][bb][swzH(bb, h)] = (ushort)(q & 0xffffu);
        H32[0][bb][swzF(bb, h)] = v;
    }
    __syncthreads();

    const int wv = tid >> 6;
    const int lane = tid & 63;

    if (wv < 4) {
        // ================= MFMA compute waves =================
        const int col = lane & 15;                   // N-col (batch) / A M-row
        const int act = col < BT;
        const int colc = act ? col : (BT - 1);       // clamped for addressing
        const int kb = (lane >> 4) * 8;              // k-offset within 32-chunk
        const int r0 = wv * 32 + (lane >> 4) * 4;    // C rows base, tile0

        // ---- A fragments: W_hh rows, split hi/lo bf16 ----
        uint4v Ahi[2][4], Alo[2][4];
#pragma unroll
        for (int tau = 0; tau < 2; ++tau) {
            const int row = wv * 32 + tau * 16 + col;
            const float* wrow = Whh + row * HH + kb;
#pragma unroll
            for (int c = 0; c < 4; ++c) {
                float4 wa = *(const float4*)(wrow + c * 32);
                float4 wb = *(const float4*)(wrow + c * 32 + 4);
                unsigned int h01 = bf16pk(wa.x, wa.y), h23 = bf16pk(wa.z, wa.w);
                unsigned int h45 = bf16pk(wb.x, wb.y), h67 = bf16pk(wb.z, wb.w);
                unsigned int l01 = bf16pk(wa.x - f_lo16(h01), wa.y - f_hi16(h01));
                unsigned int l23 = bf16pk(wa.z - f_lo16(h23), wa.w - f_hi16(h23));
                unsigned int l45 = bf16pk(wb.x - f_lo16(h45), wb.y - f_hi16(h45));
                unsigned int l67 = bf16pk(wb.z - f_lo16(h67), wb.w - f_hi16(h67));
                Ahi[tau][c] = uint4v{h01, h23, h45, h67};
                Alo[tau][c] = uint4v{l01, l23, l45, l67};
            }
        }

        // loop-invariant swizzled offsets
        int rdB[4], wrHi0, wrHi1, rdX0, rdX1, wrF0, wrF1;
#pragma unroll
        for (int c = 0; c < 4; ++c) rdB[c] = ((c * 4 + (kb >> 3)) ^ colc) << 3;
        wrHi0 = swzH(colc, r0);
        wrHi1 = swzH(colc, r0 + 16);
        rdX0 = swzF(colc, r0);
        rdX1 = swzF(colc, r0 + 16);
        wrF0 = rdX0;
        wrF1 = rdX1;

        // persistent masked state (col>=BT lanes keep zeros forever)
        uint4v bh[4] = {}, bl[4] = {};
        f32x4 xp0 = {0.f, 0.f, 0.f, 0.f}, xp1 = {0.f, 0.f, 0.f, 0.f};

        bar_lds();

        auto cwin = [&](const ushort* bhiP, const ushort* bloP, const float* xpP,
                        ushort* ohiP, ushort* oloP, float* o32P) {
            if (act) {
#pragma unroll
                for (int c = 0; c < 4; ++c) {
                    bh[c] = *(const uint4v*)(bhiP + rdB[c]);
                    bl[c] = *(const uint4v*)(bloP + rdB[c]);
                }
                xp0 = *(const f32x4*)(xpP + rdX0);
                xp1 = *(const f32x4*)(xpP + rdX1);
            }
            f32x4 a0 = xp0, a1 = {0.f, 0.f, 0.f, 0.f}, a2 = {0.f, 0.f, 0.f, 0.f};
            f32x4 c0 = xp1, c1 = {0.f, 0.f, 0.f, 0.f}, c2 = {0.f, 0.f, 0.f, 0.f};
#pragma unroll
            for (int c = 0; c < 4; ++c) {
                a0 = MFMA(Ahi[0][c], bh[c], a0);
                a1 = MFMA(Ahi[0][c], bl[c], a1);
                a2 = MFMA(Alo[0][c], bh[c], a2);
                c0 = MFMA(Ahi[1][c], bh[c], c0);
                c1 = MFMA(Ahi[1][c], bl[c], c1);
                c2 = MFMA(Alo[1][c], bh[c], c2);
            }
            f32x4 s0 = (a0 + a1) + a2;
            f32x4 s1 = (c0 + c1) + c2;
            float t0 = fast_tanh(s0.x), t1 = fast_tanh(s0.y);
            float t2 = fast_tanh(s0.z), t3 = fast_tanh(s0.w);
            float u0 = fast_tanh(s1.x), u1 = fast_tanh(s1.y);
            float u2 = fast_tanh(s1.z), u3 = fast_tanh(s1.w);
            if (act) {
                unsigned int p0 = bf16pk(t0, t1), p1 = bf16pk(t2, t3);
                unsigned int q0 = bf16pk(t0 - f_lo16(p0), t1 - f_hi16(p0));
                unsigned int q1 = bf16pk(t2 - f_lo16(p1), t3 - f_hi16(p1));
                *(uint2v*)(ohiP + wrHi0) = uint2v{p0, p1};
                *(uint2v*)(oloP + wrHi0) = uint2v{q0, q1};
                *(f32x4*)(o32P + wrF0) = f32x4{t0, t1, t2, t3};
                unsigned int p2 = bf16pk(u0, u1), p3 = bf16pk(u2, u3);
                unsigned int q2 = bf16pk(u0 - f_lo16(p2), u1 - f_hi16(p2));
                unsigned int q3 = bf16pk(u2 - f_lo16(p3), u3 - f_hi16(p3));
                *(uint2v*)(ohiP + wrHi1) = uint2v{p2, p3};
                *(uint2v*)(oloP + wrHi1) = uint2v{q2, q3};
                *(f32x4*)(o32P + wrF1) = f32x4{u0, u1, u2, u3};
            }
            bar_lds();
        };

        for (int t = 0; t < TT; t += 2) {
            cwin(&Hhi[0][colc][0], &Hlo[0][colc][0], &XP[0][colc][0],
                 &Hhi[1][colc][0], &Hlo[1][colc][0], &H32[1][colc][0]);
            cwin(&Hhi[1][colc][0], &Hlo[1][colc][0], &XP[1][colc][0],
                 &Hhi[0][colc][0], &Hlo[0][colc][0], &H32[0][colc][0]);
        }
    } else if (wv < 6) {
        // ================= xp waves (exact fp32) =================
        const int h = (wv - 4) * 64 + lane;
        const float wi0 = Wih[h * II + 0], wi1 = Wih[h * II + 1], wi2 = Wih[h * II + 2];
        const float bias = bih[h] + bhh[h];
        const int hs = (h & 3);
        const int hc = h >> 2;

        // prologue: XP[0] from xs[0]
#pragma unroll
        for (int bb = 0; bb < BT; ++bb) {
            float4 xv = xs[0][bb];
            float v = fmaf(xv.z, wi2, fmaf(xv.y, wi1, fmaf(xv.x, wi0, bias)));
            XP[0][bb][((hc ^ bb) << 2) | hs] = v;
        }
        bar_lds();

        for (int t = 0; t < TT; t += 2) {
            {   // window t: write xp[t+1] into XP[1]
#pragma unroll
                for (int bb = 0; bb < BT; ++bb) {
                    float4 xv = xs[t + 1][bb];
                    float v = fmaf(xv.z, wi2, fmaf(xv.y, wi1, fmaf(xv.x, wi0, bias)));
                    XP[1][bb][((hc ^ bb) << 2) | hs] = v;
                }
                bar_lds();
            }
            {   // window t+1: write xp[t+2] into XP[0]
                if (t + 2 < TT) {
#pragma unroll
                    for (int bb = 0; bb < BT; ++bb) {
                        float4 xv = xs[t + 2][bb];
                        float v = fmaf(xv.z, wi2, fmaf(xv.y, wi1, fmaf(xv.x, wi0, bias)));
                        XP[0][bb][((hc ^ bb) << 2) | hs] = v;
                    }
                }
                bar_lds();
            }
        }
    } else if (wv == 6) {
        // ================= hid store wave =================
        const int bb = lane >> 3;
        const int hh0 = (lane & 7) * 16;   // lane owns 16 contiguous h
        float* hb = hid + ((size_t)(b0 + bb) * TT) * HH + hh0;
        const float* s0p = &H32[0][bb][0];
        const float* s1p = &H32[1][bb][0];
        int off[4];
#pragma unroll
        for (int c = 0; c < 4; ++c) off[c] = ((((lane & 7) * 4 + c) ^ bb) << 2);

        bar_lds();
        for (int t = 0; t < TT; t += 2) {
            if (t > 0) {
                float* g = hb + (size_t)(t - 1) * HH;
#pragma unroll
                for (int c = 0; c < 4; ++c)
                    *(f32x4*)(g + c * 4) = *(const f32x4*)(s0p + off[c]);
            }
            bar_lds();
            {
                float* g = hb + (size_t)t * HH;
#pragma unroll
                for (int c = 0; c < 4; ++c)
                    *(f32x4*)(g + c * 4) = *(const f32x4*)(s1p + off[c]);
            }
            bar_lds();
        }
        {   // tail: hiddens[1023] lives in parity-0 buffer
            float* g = hb + (size_t)(TT - 1) * HH;
#pragma unroll
            for (int c = 0; c < 4; ++c)
                *(f32x4*)(g + c * 4) = *(const f32x4*)(s0p + off[c]);
        }
    } else {
        // ================= projection wave =================
        const int bb = lane >> 3;
        const int ks = lane & 7;           // k-segment [16ks,16ks+16)
        float w[3][16];
#pragma unroll
        for (int o = 0; o < 3; ++o)
#pragma unroll
            for (int j = 0; j < 4; ++j) {
                float4 v = *(const float4*)(Wout + o * HH + ks * 16 + j * 4);
                w[o][j * 4 + 0] = v.x;
                w[o][j * 4 + 1] = v.y;
                w[o][j * 4 + 2] = v.z;
                w[o][j * 4 + 3] = v.w;
            }
        const float bo0 = bout[0], bo1 = bout[1], bo2 = bout[2];
        float* ob = out + (size_t)(b0 + bb) * TT * OO;
        const float* s0p = &H32[0][bb][0];
        const float* s1p = &H32[1][bb][0];
        int off[4];
#pragma unroll
        for (int c = 0; c < 4; ++c) off[c] = (((ks * 4 + c) ^ bb) << 2);

        auto proj = [&](const float* sp, float* op) {
            f32x4 u[4];
#pragma unroll
            for (int c = 0; c < 4; ++c) u[c] = *(const f32x4*)(sp + off[c]);
            float p0 = 0.f, p1 = 0.f, p2 = 0.f;
#pragma unroll
            for (int c = 0; c < 4; ++c) {
                p0 = fmaf(w[0][c * 4 + 0], u[c].x, p0); p0 = fmaf(w[0][c * 4 + 1], u[c].y, p0);
                p0 = fmaf(w[0][c * 4 + 2], u[c].z, p0); p0 = fmaf(w[0][c * 4 + 3], u[c].w, p0);
                p1 = fmaf(w[1][c * 4 + 0], u[c].x, p1); p1 = fmaf(w[1][c * 4 + 1], u[c].y, p1);
                p1 = fmaf(w[1][c * 4 + 2], u[c].z, p1); p1 = fmaf(w[1][c * 4 + 3], u[c].w, p1);
                p2 = fmaf(w[2][c * 4 + 0], u[c].x, p2); p2 = fmaf(w[2][c * 4 + 1], u[c].y, p2);
                p2 = fmaf(w[2][c * 4 + 2], u[c].z, p2); p2 = fmaf(w[2][c * 4 + 3], u[c].w, p2);
            }
            p0 = dpp_add<DPP_XOR1>(p0); p0 = dpp_add<DPP_XOR2>(p0); p0 = dpp_add<DPP_HALF_MIRROR>(p0);
            p1 = dpp_add<DPP_XOR1>(p1); p1 = dpp_add<DPP_XOR2>(p1); p1 = dpp_add<DPP_HALF_MIRROR>(p1);
            p2 = dpp_add<DPP_XOR1>(p2); p2 = dpp_add<DPP_XOR2>(p2); p2 = dpp_add<DPP_HALF_MIRROR>(p2);
            if (ks == 0) {
                op[0] = p0 + bo0;
                op[1] = p1 + bo1;
                op[2] = p2 + bo2;
            }
        };

        bar_lds();
        for (int t = 0; t < TT; t += 2) {
            if (t > 0) proj(s0p, ob + (size_t)(t - 1) * OO);
            bar_lds();
            proj(s1p, ob + (size_t)t * OO);
            bar_lds();
        }
        proj(s0p, ob + (size_t)(TT - 1) * OO);
    }
}

extern "C" void kernel_launch(void* const* d_in, const int* in_sizes, int n_in,
                              void* d_out, int out_size, void* d_ws, size_t ws_size,
                              hipStream_t stream) {
    const float* x    = (const float*)d_in[0];  // [256,1024,3]
    const float* Wih  = (const float*)d_in[1];  // [128,3]
    const float* Whh  = (const float*)d_in[2];  // [128,128]
    const float* bih  = (const float*)d_in[3];  // [128]
    const float* bhh  = (const float*)d_in[4];  // [128]
    const float* h0   = (const float*)d_in[5];  // [1,128]
    const float* Wout = (const float*)d_in[6];  // [3,128]
    const float* bout = (const float*)d_in[7];  // [3]

    float* out = (float*)d_out;                 // [B,T,O] first
    float* hid = out + (size_t)BB * TT * OO;    // then [B,T,H]

    rnn_kernel<<<NBLK, NT, 0, stream>>>(x, Wih, Whh, bih, bhh, h0, Wout, bout, out, hid);
}